// Round 4
// baseline (266.279 us; speedup 1.0000x reference)
//
#include <hip/hip_runtime.h>
#include <math.h>

// ---------------------------------------------------------------------------
// Kernel A: per-token metadata (pos index into pos_emb, bucket into ts_emb).
// One thread per token. B=32 sequences -> 6-step binary search over offsets.
// ---------------------------------------------------------------------------
__global__ void hstu_meta_kernel(const int* __restrict__ seq_lengths,
                                 const int* __restrict__ seq_offsets,
                                 const int* __restrict__ num_targets,
                                 const int* __restrict__ seq_timestamps,
                                 int* __restrict__ pos_idx,
                                 int* __restrict__ bucket_idx,
                                 int T, int B, int NPOS, int NTIME) {
    int t = blockIdx.x * blockDim.x + threadIdx.x;
    if (t >= T) return;

    // largest sid with seq_offsets[sid] <= t  (offsets[0]=0, offsets[B]=T)
    int lo = 0, hi = B;
    while (hi - lo > 1) {
        int mid = (lo + hi) >> 1;
        if (seq_offsets[mid] <= t) lo = mid; else hi = mid;
    }
    const int sid   = lo;
    const int off   = seq_offsets[sid];
    const int L     = seq_lengths[sid];
    const int local = t - off;

    // position bucket (interleave_targets=False): targets share first-target pos
    int high = L - num_targets[sid];
    if (high > NPOS - 1) high = NPOS - 1;
    int pos = local < high ? local : high;
    if (pos < 0) pos = 0;
    if (pos > NPOS - 1) pos = NPOS - 1;

    // time bucket: floor(sqrt(query_ts - ts[t])) clamped to [0, NTIME]
    const int qts   = seq_timestamps[off + L - 1];
    int delta = qts - seq_timestamps[t];
    if (delta < 0) delta = 0;
    int bucket = (int)floorf(sqrtf((float)delta));
    if (bucket < 0) bucket = 0;
    if (bucket > NTIME) bucket = NTIME;

    pos_idx[t]    = pos;
    bucket_idx[t] = bucket;
}

// ---------------------------------------------------------------------------
// Kernel B: hot fused gather + scale + add, float4-vectorized.
// idx indexes float4 elements of the (T, D) output; t = idx >> C4_SHIFT.
// 128 consecutive lanes share one row -> metadata loads are broadcast L1 hits.
// ---------------------------------------------------------------------------
template <int C4_SHIFT>
__global__ void __launch_bounds__(256)
hstu_fuse_kernel_pow2(const float4* __restrict__ emb,
                      const float4* __restrict__ pos_emb,
                      const float4* __restrict__ ts_emb,
                      const int* __restrict__ pos_idx,
                      const int* __restrict__ bucket_idx,
                      float4* __restrict__ out,
                      int total4, float alpha) {
    const int stride = gridDim.x * blockDim.x;
    constexpr int C4 = 1 << C4_SHIFT;
    for (int idx = blockIdx.x * blockDim.x + threadIdx.x; idx < total4; idx += stride) {
        const int t = idx >> C4_SHIFT;
        const int c = idx & (C4 - 1);
        const int p = pos_idx[t];
        const int b = bucket_idx[t];
        const float4 e  = emb[idx];
        const float4 pe = pos_emb[(long)p * C4 + c];
        const float4 te = ts_emb[(long)b * C4 + c];
        float4 o;
        o.x = fmaf(e.x, alpha, pe.x + te.x);
        o.y = fmaf(e.y, alpha, pe.y + te.y);
        o.z = fmaf(e.z, alpha, pe.z + te.z);
        o.w = fmaf(e.w, alpha, pe.w + te.w);
        out[idx] = o;
    }
}

// generic fallback (D/4 not a power of two)
__global__ void __launch_bounds__(256)
hstu_fuse_kernel_gen(const float4* __restrict__ emb,
                     const float4* __restrict__ pos_emb,
                     const float4* __restrict__ ts_emb,
                     const int* __restrict__ pos_idx,
                     const int* __restrict__ bucket_idx,
                     float4* __restrict__ out,
                     int total4, int c4, float alpha) {
    const int stride = gridDim.x * blockDim.x;
    for (int idx = blockIdx.x * blockDim.x + threadIdx.x; idx < total4; idx += stride) {
        const int t = idx / c4;
        const int c = idx - t * c4;
        const int p = pos_idx[t];
        const int b = bucket_idx[t];
        const float4 e  = emb[idx];
        const float4 pe = pos_emb[(long)p * c4 + c];
        const float4 te = ts_emb[(long)b * c4 + c];
        float4 o;
        o.x = fmaf(e.x, alpha, pe.x + te.x);
        o.y = fmaf(e.y, alpha, pe.y + te.y);
        o.z = fmaf(e.z, alpha, pe.z + te.z);
        o.w = fmaf(e.w, alpha, pe.w + te.w);
        out[idx] = o;
    }
}

extern "C" void kernel_launch(void* const* d_in, const int* in_sizes, int n_in,
                              void* d_out, int out_size, void* d_ws, size_t ws_size,
                              hipStream_t stream) {
    // Input order: max_seq_len, seq_lengths, seq_offsets, seq_embeddings,
    //              num_targets, seq_timestamps, pos_emb, ts_emb
    const int* seq_lengths    = (const int*)d_in[1];
    const int* seq_offsets    = (const int*)d_in[2];
    const float* seq_emb      = (const float*)d_in[3];
    const int* num_targets    = (const int*)d_in[4];
    const int* seq_timestamps = (const int*)d_in[5];
    const float* pos_emb      = (const float*)d_in[6];
    const float* ts_emb       = (const float*)d_in[7];
    float* out                = (float*)d_out;

    const int B     = in_sizes[1];
    const int T     = in_sizes[5];
    const int D     = in_sizes[3] / T;
    const int NPOS  = in_sizes[6] / D;
    const int NTIME = in_sizes[7] / D - 1;
    const float alpha = sqrtf((float)D);

    int* pos_idx    = (int*)d_ws;
    int* bucket_idx = pos_idx + T;

    // Kernel A: per-token metadata
    {
        const int block = 256;
        const int grid  = (T + block - 1) / block;
        hstu_meta_kernel<<<grid, block, 0, stream>>>(
            seq_lengths, seq_offsets, num_targets, seq_timestamps,
            pos_idx, bucket_idx, T, B, NPOS, NTIME);
    }

    // Kernel B: fused gather + scale + add
    {
        const int c4     = D / 4;
        const long total4l = (long)T * c4;
        const int total4 = (int)total4l;  // 8.4M for this problem, fits int
        const int block  = 256;
        int grid = (int)((total4l + block - 1) / block);
        const int grid_cap = 256 * 8;  // 256 CUs x 8 blocks (4 waves each)
        if (grid > grid_cap) grid = grid_cap;

        if (c4 == 128) {
            hstu_fuse_kernel_pow2<7><<<grid, block, 0, stream>>>(
                (const float4*)seq_emb, (const float4*)pos_emb, (const float4*)ts_emb,
                pos_idx, bucket_idx, (float4*)out, total4, alpha);
        } else if (c4 == 64) {
            hstu_fuse_kernel_pow2<6><<<grid, block, 0, stream>>>(
                (const float4*)seq_emb, (const float4*)pos_emb, (const float4*)ts_emb,
                pos_idx, bucket_idx, (float4*)out, total4, alpha);
        } else if (c4 == 256) {
            hstu_fuse_kernel_pow2<8><<<grid, block, 0, stream>>>(
                (const float4*)seq_emb, (const float4*)pos_emb, (const float4*)ts_emb,
                pos_idx, bucket_idx, (float4*)out, total4, alpha);
        } else {
            hstu_fuse_kernel_gen<<<grid, block, 0, stream>>>(
                (const float4*)seq_emb, (const float4*)pos_emb, (const float4*)ts_emb,
                pos_idx, bucket_idx, (float4*)out, total4, c4, alpha);
        }
    }
}

// Round 7
// 261.049 us; speedup vs baseline: 1.0200x; 1.0200x over previous
//
#include <hip/hip_runtime.h>
#include <math.h>

// Native vector type: __builtin_nontemporal_load/store require scalar,
// pointer, or NATIVE vector element types (HIP_vector_type float4 is a
// struct and is rejected). ext_vector_type(4) float compiles to the same
// dwordx4 accesses.
typedef float f32x4 __attribute__((ext_vector_type(4)));

// ---------------------------------------------------------------------------
// Kernel A: per-token metadata. One thread per token; 6-step binary search
// over B=32 offsets. Writes a combined int2 {pos, bucket} so the hot kernel
// needs ONE 8B index load per row instead of two 4B loads.
// ---------------------------------------------------------------------------
__global__ void hstu_meta_kernel(const int* __restrict__ seq_lengths,
                                 const int* __restrict__ seq_offsets,
                                 const int* __restrict__ num_targets,
                                 const int* __restrict__ seq_timestamps,
                                 int2* __restrict__ meta,
                                 int T, int B, int NPOS, int NTIME) {
    int t = blockIdx.x * blockDim.x + threadIdx.x;
    if (t >= T) return;

    // largest sid with seq_offsets[sid] <= t  (offsets[0]=0, offsets[B]=T)
    int lo = 0, hi = B;
    while (hi - lo > 1) {
        int mid = (lo + hi) >> 1;
        if (seq_offsets[mid] <= t) lo = mid; else hi = mid;
    }
    const int sid   = lo;
    const int off   = seq_offsets[sid];
    const int L     = seq_lengths[sid];
    const int local = t - off;

    // position bucket (interleave_targets=False): targets share first-target pos
    int high = L - num_targets[sid];
    if (high > NPOS - 1) high = NPOS - 1;
    int pos = local < high ? local : high;
    if (pos < 0) pos = 0;
    if (pos > NPOS - 1) pos = NPOS - 1;

    // time bucket: floor(sqrt(query_ts - ts[t])) clamped to [0, NTIME]
    const int qts   = seq_timestamps[off + L - 1];
    int delta = qts - seq_timestamps[t];
    if (delta < 0) delta = 0;
    int bucket = (int)floorf(sqrtf((float)delta));
    if (bucket < 0) bucket = 0;
    if (bucket > NTIME) bucket = NTIME;

    meta[t] = make_int2(pos, bucket);
}

// ---------------------------------------------------------------------------
// Kernel B (hot): wave-per-row fused gather + scale + add.
// One 64-lane wave owns one full row of D floats (C4 = D/4 float4s,
// F4PL = C4/64 float4s per lane). Per row: 1 int2 idx load, then 3*F4PL
// INDEPENDENT dwordx4 loads issued back-to-back (MLP), next row's idx
// prefetched during compute. emb/out use nontemporal hints so the 268 MB
// stream doesn't evict the ~21 MB pos/ts tables from L2.
// ---------------------------------------------------------------------------
template <int C4S>   // log2(float4s per row); D=512 -> C4=128 -> C4S=7
__global__ void __launch_bounds__(256)
hstu_fuse_wave_row(const f32x4* __restrict__ emb,
                   const f32x4* __restrict__ pos_emb,
                   const f32x4* __restrict__ ts_emb,
                   const int2* __restrict__ meta,
                   f32x4* __restrict__ out,
                   int T, float alpha) {
    constexpr int C4   = 1 << C4S;   // float4s per row
    constexpr int F4PL = C4 >> 6;    // float4s per lane (2 for D=512)
    static_assert(F4PL >= 1, "row must span at least one float4 per lane");

    const int lane = threadIdx.x & 63;
    const int wpb  = blockDim.x >> 6;
    const int nw   = gridDim.x * wpb;
    int t = blockIdx.x * wpb + (threadIdx.x >> 6);
    if (t >= T) return;

    int2 m = meta[t];
    while (true) {
        const int tn = t + nw;
        int2 mn = m;
        if (tn < T) mn = meta[tn];   // prefetch next row's indices

        const f32x4* ep = emb     + (((size_t)t)   << C4S) + lane;
        const f32x4* pp = pos_emb + (((size_t)m.x) << C4S) + lane;
        const f32x4* tp = ts_emb  + (((size_t)m.y) << C4S) + lane;

        f32x4 e[F4PL], p[F4PL], q[F4PL];
#pragma unroll
        for (int j = 0; j < F4PL; ++j) e[j] = __builtin_nontemporal_load(ep + 64 * j);
#pragma unroll
        for (int j = 0; j < F4PL; ++j) p[j] = pp[64 * j];
#pragma unroll
        for (int j = 0; j < F4PL; ++j) q[j] = tp[64 * j];

        f32x4* op = out + (((size_t)t) << C4S) + lane;
#pragma unroll
        for (int j = 0; j < F4PL; ++j) {
            f32x4 o;
            o.x = fmaf(e[j].x, alpha, p[j].x + q[j].x);
            o.y = fmaf(e[j].y, alpha, p[j].y + q[j].y);
            o.z = fmaf(e[j].z, alpha, p[j].z + q[j].z);
            o.w = fmaf(e[j].w, alpha, p[j].w + q[j].w);
            __builtin_nontemporal_store(o, op + 64 * j);
        }

        if (tn >= T) break;
        t = tn;
        m = mn;
    }
}

// ---------------------------------------------------------------------------
// Generic fallback (D/4 not a multiple of 64): per-float4 mapping.
// ---------------------------------------------------------------------------
__global__ void __launch_bounds__(256)
hstu_fuse_kernel_gen(const f32x4* __restrict__ emb,
                     const f32x4* __restrict__ pos_emb,
                     const f32x4* __restrict__ ts_emb,
                     const int2* __restrict__ meta,
                     f32x4* __restrict__ out,
                     int total4, int c4, float alpha) {
    const int stride = gridDim.x * blockDim.x;
    for (int idx = blockIdx.x * blockDim.x + threadIdx.x; idx < total4; idx += stride) {
        const int t = idx / c4;
        const int c = idx - t * c4;
        const int2 m = meta[t];
        const f32x4 e  = emb[idx];
        const f32x4 pe = pos_emb[(size_t)m.x * c4 + c];
        const f32x4 te = ts_emb[(size_t)m.y * c4 + c];
        f32x4 o;
        o.x = fmaf(e.x, alpha, pe.x + te.x);
        o.y = fmaf(e.y, alpha, pe.y + te.y);
        o.z = fmaf(e.z, alpha, pe.z + te.z);
        o.w = fmaf(e.w, alpha, pe.w + te.w);
        out[idx] = o;
    }
}

extern "C" void kernel_launch(void* const* d_in, const int* in_sizes, int n_in,
                              void* d_out, int out_size, void* d_ws, size_t ws_size,
                              hipStream_t stream) {
    // Input order: max_seq_len, seq_lengths, seq_offsets, seq_embeddings,
    //              num_targets, seq_timestamps, pos_emb, ts_emb
    const int* seq_lengths    = (const int*)d_in[1];
    const int* seq_offsets    = (const int*)d_in[2];
    const float* seq_emb      = (const float*)d_in[3];
    const int* num_targets    = (const int*)d_in[4];
    const int* seq_timestamps = (const int*)d_in[5];
    const float* pos_emb      = (const float*)d_in[6];
    const float* ts_emb       = (const float*)d_in[7];
    float* out                = (float*)d_out;

    const int B     = in_sizes[1];
    const int T     = in_sizes[5];
    const int D     = in_sizes[3] / T;
    const int NPOS  = in_sizes[6] / D;
    const int NTIME = in_sizes[7] / D - 1;
    const float alpha = sqrtf((float)D);

    int2* meta = (int2*)d_ws;

    // Kernel A: per-token metadata
    {
        const int block = 256;
        const int grid  = (T + block - 1) / block;
        hstu_meta_kernel<<<grid, block, 0, stream>>>(
            seq_lengths, seq_offsets, num_targets, seq_timestamps,
            meta, T, B, NPOS, NTIME);
    }

    // Kernel B: fused gather + scale + add
    const int c4 = D / 4;
    const int block = 256;
    const int wpb = block / 64;

    if (c4 == 128 || c4 == 64 || c4 == 256) {
        // wave-per-row: total waves needed = T; cap grid at 2048 blocks
        // (8192 waves = 32 waves/CU on 256 CUs) and grid-stride the rest.
        int grid = (T + wpb - 1) / wpb;
        if (grid > 2048) grid = 2048;
        if (c4 == 128) {
            hstu_fuse_wave_row<7><<<grid, block, 0, stream>>>(
                (const f32x4*)seq_emb, (const f32x4*)pos_emb, (const f32x4*)ts_emb,
                meta, (f32x4*)out, T, alpha);
        } else if (c4 == 64) {
            hstu_fuse_wave_row<6><<<grid, block, 0, stream>>>(
                (const f32x4*)seq_emb, (const f32x4*)pos_emb, (const f32x4*)ts_emb,
                meta, (f32x4*)out, T, alpha);
        } else {
            hstu_fuse_wave_row<8><<<grid, block, 0, stream>>>(
                (const f32x4*)seq_emb, (const f32x4*)pos_emb, (const f32x4*)ts_emb,
                meta, (f32x4*)out, T, alpha);
        }
    } else {
        const long total4l = (long)T * c4;
        const int total4 = (int)total4l;
        int grid = (int)((total4l + block - 1) / block);
        if (grid > 2048) grid = 2048;
        hstu_fuse_kernel_gen<<<grid, block, 0, stream>>>(
            (const f32x4*)seq_emb, (const f32x4*)pos_emb, (const f32x4*)ts_emb,
            meta, (f32x4*)out, total4, c4, alpha);
    }
}